// Round 8
// baseline (466.870 us; speedup 1.0000x reference)
//
#include <hip/hip_runtime.h>
#include <stdint.h>

static constexpr int CI = 16;
static constexpr int CO = 32;
static constexpr int H  = 300000;
static constexpr int K  = 27;
static constexpr float BN_EPS = 1e-5f;

// ---------- bf16 helpers ----------
__device__ __forceinline__ unsigned short f2bf(float f) {
    union { float f; unsigned int i; } v; v.f = f;
    unsigned int x = v.i;
    return (unsigned short)((x + 0x7fffu + ((x >> 16) & 1u)) >> 16);  // RNE
}
// one word -> two floats, 2 VALU ops (lshl + and)
__device__ __forceinline__ void unpack2(unsigned int u, float& lo, float& hi) {
    union { unsigned int i; float f; } a, b;
    a.i = u << 16;
    b.i = u & 0xffff0000u;
    lo = a.f; hi = b.f;
}

// ---------- kernel 1: fused prep ----------
// x fp32 (CI,H) -> xT bf16 (H,CI);  w fp32 (o,i,k) -> wf[k][o*CI+i];  zero stats[64]
__global__ __launch_bounds__(256) void prep(const float* __restrict__ x,
                                            const float* __restrict__ w,
                                            unsigned short* __restrict__ xT,
                                            float* __restrict__ wf,
                                            float* __restrict__ stats) {
    int h = blockIdx.x * 256 + threadIdx.x;
    if (h < H) {
        union { unsigned short s[CI]; uint4 q[2]; } v;
        #pragma unroll
        for (int i = 0; i < CI; ++i) v.s[i] = f2bf(x[(size_t)i * H + h]);  // coalesced per i
        uint4* dst = reinterpret_cast<uint4*>(xT + (size_t)h * CI);
        dst[0] = v.q[0];
        dst[1] = v.q[1];
    }
    if (blockIdx.x == 0) {
        for (int t = threadIdx.x; t < CO * CI * K; t += 256) {
            int k  = t % K;
            int oi = t / K;                 // oi = o*CI + i (source is (o,i,k) flat)
            wf[k * (CO * CI) + oi] = w[t];
        }
        if (threadIdx.x < 64) stats[threadIdx.x] = 0.f;   // gsum[32] ++ gsq[32]
    }
}

// ---------- kernel 2: conv with cooperative double-buffered LDS gather ----------
// Block: 256 threads = 128 h. Compute: t<128 -> outputs 0-15, t>=128 -> 16-31.
// Gather: per k the block fetches its 128 rows EXACTLY ONCE — lane pairs
// (t>>1 = row j, t&1 = 16B half) so both halves of a row sit in one wave-inst
// and one cache line (HW merges) -> ~4x fewer L1 requests than per-thread gather.
// Rows land in a 2 x 4KB LDS double buffer; load for k+1 issues before the
// 512-cycle FMA block of k -> latency hidden; one barrier per k.
__global__ __launch_bounds__(256) void conv(const unsigned short* __restrict__ xT,
                                            const float* __restrict__ wf,
                                            const int* __restrict__ neigh,
                                            float* __restrict__ out,
                                            float* __restrict__ stats) {
    __shared__ int  snb[128 * K];          // [j][k]
    __shared__ uint4 sxr[2][128 * 2];      // [buf][j*2 + half] 16B units

    const int t    = threadIdx.x;
    const int hl   = t & 127;
    const int half = __builtin_amdgcn_readfirstlane(t >> 7);   // wave-uniform 0/1
    const int h    = blockIdx.x * 128 + hl;

    // stage this block's neighbor indices coalesced into LDS
    {
        const int base = blockIdx.x * 128 * K;
        for (int s = t; s < 128 * K; s += 256) {
            int g = base + s;
            snb[s] = (g < H * K) ? neigh[g] : -1;   // also covers j beyond H in last block
        }
    }
    __syncthreads();

    const int gj = t >> 1;    // gather row 0..127
    const int gh = t & 1;     // gather half 0/1

    // prologue: gather k=0 into buffer 0
    {
        int idx = snb[gj * K + 0];
        const uint4* p = reinterpret_cast<const uint4*>(
            xT + (size_t)(idx < 0 ? 0 : idx) * CI) + gh;
        uint4 v = *p;
        if (idx < 0) { v.x = v.y = v.z = v.w = 0u; }
        sxr[0][gj * 2 + gh] = v;
    }
    __syncthreads();

    float acc[16];
    #pragma unroll
    for (int o = 0; o < 16; ++o) acc[o] = 0.f;

    const float* wh = wf + half * (16 * CI);   // this half's weights within each k-block

    for (int k = 0; k < K; ++k) {
        const int cur = k & 1;

        // issue next gather early (latency hidden behind the FMA block)
        uint4 nv;
        int nidx = 0;
        const bool have_next = (k + 1 < K);
        if (have_next) {
            nidx = snb[gj * K + (k + 1)];
            const uint4* p = reinterpret_cast<const uint4*>(
                xT + (size_t)(nidx < 0 ? 0 : nidx) * CI) + gh;
            nv = *p;
        }

        // consume current buffer (zeros pre-stored for invalid/out-of-range rows)
        uint4 ra = sxr[cur][hl * 2 + 0];
        uint4 rb = sxr[cur][hl * 2 + 1];
        float xi[CI];
        unpack2(ra.x, xi[0],  xi[1]);  unpack2(ra.y, xi[2],  xi[3]);
        unpack2(ra.z, xi[4],  xi[5]);  unpack2(ra.w, xi[6],  xi[7]);
        unpack2(rb.x, xi[8],  xi[9]);  unpack2(rb.y, xi[10], xi[11]);
        unpack2(rb.z, xi[12], xi[13]); unpack2(rb.w, xi[14], xi[15]);

        const float* wk = wh + k * (CO * CI);   // wave-uniform -> scalar loads
        #pragma unroll
        for (int o = 0; o < 16; ++o) {
            float s = acc[o];
            #pragma unroll
            for (int i = 0; i < CI; ++i) s = fmaf(wk[o * CI + i], xi[i], s);
            acc[o] = s;
        }

        // stash next rows into the other buffer
        if (have_next) {
            if (nidx < 0) { nv.x = nv.y = nv.z = nv.w = 0u; }
            sxr[cur ^ 1][gj * 2 + gh] = nv;
        }
        __syncthreads();   // separates this k's writes from next k's reads
    }

    if (h < H) {
        #pragma unroll
        for (int o = 0; o < 16; ++o)
            out[(size_t)(half * 16 + o) * H + h] = acc[o];   // coalesced over h
    }

    // fused BN statistics: butterfly per output, one atomic per wave per output
    const unsigned lane = t & 63u;
    float mySum = 0.f, mySq = 0.f;
    #pragma unroll
    for (int o = 0; o < 16; ++o) {
        float v = acc[o];
        float q = v * v;
        #pragma unroll
        for (int d = 32; d > 0; d >>= 1) {
            v += __shfl_xor(v, d, 64);
            q += __shfl_xor(q, d, 64);
        }
        if (lane == (unsigned)o) { mySum = v; mySq = q; }
    }
    if (lane < 16u) {
        atomicAdd(&stats[half * 16 + lane], mySum);        // gsum
        atomicAdd(&stats[32 + half * 16 + lane], mySq);    // gsq
    }
}

// ---------- kernel 3: BN apply (scale/shift recomputed per thread from stats) ----------
__global__ __launch_bounds__(256) void bn_apply(float* __restrict__ out,
                                                const float* __restrict__ stats,
                                                const float* __restrict__ gamma,
                                                const float* __restrict__ beta) {
    size_t t = (size_t)blockIdx.x * 256 + threadIdx.x;
    size_t base = t * 4;
    if (base >= (size_t)CO * H) return;
    int o = (int)(base / (size_t)H);     // H % 4 == 0 -> float4 never crosses channels
    const float invH = 1.f / (float)H;
    float m   = stats[o] * invH;
    float var = stats[32 + o] * invH - m * m;
    float inv = rsqrtf(var + BN_EPS);
    float sc  = gamma[o] * inv;
    float sh  = beta[o] - m * sc;
    float4* p = reinterpret_cast<float4*>(out + base);
    float4 q = *p;
    q.x = q.x * sc + sh;
    q.y = q.y * sc + sh;
    q.z = q.z * sc + sh;
    q.w = q.w * sc + sh;
    *p = q;
}

// ---------- launch ----------
extern "C" void kernel_launch(void* const* d_in, const int* in_sizes, int n_in,
                              void* d_out, int out_size, void* d_ws, size_t ws_size,
                              hipStream_t stream) {
    const float* x     = (const float*)d_in[0];   // fp32 (1,CI,H,1)
    const float* w     = (const float*)d_in[1];   // fp32 (CO,CI,K)
    const float* gamma = (const float*)d_in[2];   // fp32 (CO)
    const float* beta  = (const float*)d_in[3];   // fp32 (CO)
    const int*   neigh = (const int*)d_in[4];     // int32 (H,K)
    float*       out   = (float*)d_out;           // fp32 (CO,H)

    char* ws = (char*)d_ws;
    const size_t XT_OFF    = 0;                    // H*CI*2    = 9,600,000 B
    const size_t WF_OFF    = 9600000;              // CO*CI*K*4 = 55,296 B
    const size_t STATS_OFF = 9655296;              // 64 floats
    unsigned short* xT    = (unsigned short*)(ws + XT_OFF);
    float*          wf    = (float*)(ws + WF_OFF);
    float*          stats = (float*)(ws + STATS_OFF);

    const int HBP = (H + 255) / 256;               // 1172 (prep)
    prep<<<HBP, 256, 0, stream>>>(x, w, xT, wf, stats);

    const int HBC = (H + 127) / 128;               // 2344 (conv: 128 h/block)
    conv<<<HBC, 256, 0, stream>>>(xT, wf, neigh, out, stats);

    const int NBN = (CO * H / 4 + 255) / 256;      // 9375
    bn_apply<<<NBN, 256, 0, stream>>>(out, stats, gamma, beta);
}

// Round 10
// 297.469 us; speedup vs baseline: 1.5695x; 1.5695x over previous
//
#include <hip/hip_runtime.h>
#include <hip/hip_fp16.h>
#include <stdint.h>

static constexpr int CI = 16;
static constexpr int CO = 32;
static constexpr int H  = 300000;
static constexpr int K  = 27;
static constexpr float BN_EPS = 1e-5f;

// ---------- f16 helpers ----------
typedef _Float16 h2_t __attribute__((ext_vector_type(2)));

__device__ __forceinline__ unsigned int pack_f16(float lo, float hi) {
    union { h2_t h; unsigned int u; } v;
    v.h[0] = (_Float16)lo;
    v.h[1] = (_Float16)hi;
    return v.u;
}

// acc += a.lo*b.lo + a.hi*b.hi  (v_dot2_f32_f16)
__device__ __forceinline__ float dot2f(unsigned int a, unsigned int b, float c) {
#if __has_builtin(__builtin_amdgcn_fdot2)
    union { unsigned int u; h2_t h; } ua, ub;
    ua.u = a; ub.u = b;
    return __builtin_amdgcn_fdot2(ua.h, ub.h, c, false);
#else
    union { unsigned int u; h2_t h; } ua, ub;
    ua.u = a; ub.u = b;
    float r = fmaf((float)ua.h[0], (float)ub.h[0], c);
    return fmaf((float)ua.h[1], (float)ub.h[1], r);
#endif
}

// ---------- kernel 1: fused prep ----------
// x fp32 (CI,H) -> xTp f16-pair rows (H x 8 dwords, 32 B/row);
// w fp32 (o,i,k) -> wp[(k*32+o)*8+j] = (w[o,2j,k], w[o,2j+1,k]) f16 pairs;
// zero stats[64].
__global__ __launch_bounds__(256) void prep(const float* __restrict__ x,
                                            const float* __restrict__ w,
                                            unsigned int* __restrict__ xTp,
                                            unsigned int* __restrict__ wp,
                                            float* __restrict__ stats) {
    int h = blockIdx.x * 256 + threadIdx.x;
    if (h < H) {
        unsigned int r[8];
        #pragma unroll
        for (int j = 0; j < 8; ++j)
            r[j] = pack_f16(x[(size_t)(2 * j) * H + h], x[(size_t)(2 * j + 1) * H + h]);
        uint4* dst = reinterpret_cast<uint4*>(xTp + (size_t)h * 8);
        dst[0] = make_uint4(r[0], r[1], r[2], r[3]);
        dst[1] = make_uint4(r[4], r[5], r[6], r[7]);
    }
    if (blockIdx.x == 0) {
        for (int idx = threadIdx.x; idx < K * CO * 8; idx += 256) {
            int j = idx & 7;
            int o = (idx >> 3) & 31;
            int k = idx >> 8;
            float lo = w[((size_t)o * CI + 2 * j) * K + k];
            float hi = w[((size_t)o * CI + 2 * j + 1) * K + k];
            wp[idx] = pack_f16(lo, hi);
        }
        if (threadIdx.x < 64) stats[threadIdx.x] = 0.f;   // gsum[32] ++ gsq[32]
    }
}

// ---------- kernel 2: gathered conv (f16 dot2) + fused BN stats ----------
// Block: 256 threads = 128 h. t<128 -> outputs 0-15, t>=128 -> outputs 16-31
// (half = readfirstlane -> weight addresses wave-uniform -> scalar loads).
// Per-thread gather of 32 B rows, 1-deep pipeline; inner loop is 16x8 dot2
// (128 VALU ops/k vs 288 for fp32+unpack — the R6 bottleneck halved).
__global__ __launch_bounds__(256) void conv(const unsigned int* __restrict__ xTp,
                                            const unsigned int* __restrict__ wp,
                                            const int* __restrict__ neigh,
                                            float* __restrict__ out,
                                            float* __restrict__ stats) {
    __shared__ int snb[128 * K];
    const int t    = threadIdx.x;
    const int hl   = t & 127;
    const int half = __builtin_amdgcn_readfirstlane(t >> 7);   // wave-uniform 0/1
    const int h    = blockIdx.x * 128 + hl;

    // stage this block's neighbor indices coalesced into LDS (nontemporal stream)
    {
        const int base = blockIdx.x * 128 * K;
        for (int s = t; s < 128 * K; s += 256) {
            int g = base + s;
            snb[s] = (g < H * K) ? __builtin_nontemporal_load(&neigh[g]) : -1;
        }
    }
    __syncthreads();

    float acc[16];
    #pragma unroll
    for (int o = 0; o < 16; ++o) acc[o] = 0.f;

    if (h < H) {
        const int* np = &snb[hl * K];
        const unsigned int* wh = wp + half * 128;   // this half's 16 outputs x 8 pairs

        // prologue: prefetch k = 0
        int idx = np[0];
        const uint4* p0 = reinterpret_cast<const uint4*>(
            xTp + (size_t)(idx < 0 ? 0 : idx) * 8);
        uint4 a = p0[0];
        uint4 b = p0[1];

        for (int k = 0; k < K; ++k) {
            const int nidx = (k + 1 < K) ? np[k + 1] : 0;
            const uint4* p1 = reinterpret_cast<const uint4*>(
                xTp + (size_t)(nidx < 0 ? 0 : nidx) * 8);
            uint4 na = p1[0];
            uint4 nb = p1[1];

            if (idx < 0) {                      // cndmask zero for invalid neighbor
                a.x = a.y = a.z = a.w = 0u;
                b.x = b.y = b.z = b.w = 0u;
            }

            const unsigned int* wk = wh + k * 256;   // wave-uniform -> scalar loads
            #pragma unroll
            for (int o = 0; o < 16; ++o) {
                float s = acc[o];
                s = dot2f(a.x, wk[o * 8 + 0], s);
                s = dot2f(a.y, wk[o * 8 + 1], s);
                s = dot2f(a.z, wk[o * 8 + 2], s);
                s = dot2f(a.w, wk[o * 8 + 3], s);
                s = dot2f(b.x, wk[o * 8 + 4], s);
                s = dot2f(b.y, wk[o * 8 + 5], s);
                s = dot2f(b.z, wk[o * 8 + 6], s);
                s = dot2f(b.w, wk[o * 8 + 7], s);
                acc[o] = s;
            }

            idx = nidx; a = na; b = nb;
        }
        #pragma unroll
        for (int o = 0; o < 16; ++o)
            out[(size_t)(half * 16 + o) * H + h] = acc[o];   // coalesced over h
    }

    // fused BN statistics: butterfly per output, one atomic per wave per output
    const unsigned lane = t & 63u;
    float mySum = 0.f, mySq = 0.f;
    #pragma unroll
    for (int o = 0; o < 16; ++o) {
        float v = acc[o];
        float q = v * v;
        #pragma unroll
        for (int d = 32; d > 0; d >>= 1) {
            v += __shfl_xor(v, d, 64);
            q += __shfl_xor(q, d, 64);
        }
        if (lane == (unsigned)o) { mySum = v; mySq = q; }
    }
    if (lane < 16u) {
        atomicAdd(&stats[half * 16 + lane], mySum);        // gsum
        atomicAdd(&stats[32 + half * 16 + lane], mySq);    // gsq
    }
}

// ---------- kernel 3: BN apply (scale/shift recomputed per thread from stats) ----------
__global__ __launch_bounds__(256) void bn_apply(float* __restrict__ out,
                                                const float* __restrict__ stats,
                                                const float* __restrict__ gamma,
                                                const float* __restrict__ beta) {
    size_t t = (size_t)blockIdx.x * 256 + threadIdx.x;
    size_t base = t * 4;
    if (base >= (size_t)CO * H) return;
    int o = (int)(base / (size_t)H);     // H % 4 == 0 -> float4 never crosses channels
    const float invH = 1.f / (float)H;
    float m   = stats[o] * invH;
    float var = stats[32 + o] * invH - m * m;
    float inv = rsqrtf(var + BN_EPS);
    float sc  = gamma[o] * inv;
    float sh  = beta[o] - m * sc;
    float4* p = reinterpret_cast<float4*>(out + base);
    float4 q = *p;
    q.x = q.x * sc + sh;
    q.y = q.y * sc + sh;
    q.z = q.z * sc + sh;
    q.w = q.w * sc + sh;
    *p = q;
}

// ---------- launch ----------
extern "C" void kernel_launch(void* const* d_in, const int* in_sizes, int n_in,
                              void* d_out, int out_size, void* d_ws, size_t ws_size,
                              hipStream_t stream) {
    const float* x     = (const float*)d_in[0];   // fp32 (1,CI,H,1)
    const float* w     = (const float*)d_in[1];   // fp32 (CO,CI,K)
    const float* gamma = (const float*)d_in[2];   // fp32 (CO)
    const float* beta  = (const float*)d_in[3];   // fp32 (CO)
    const int*   neigh = (const int*)d_in[4];     // int32 (H,K)
    float*       out   = (float*)d_out;           // fp32 (CO,H)

    char* ws = (char*)d_ws;
    const size_t XT_OFF    = 0;                    // H*8*4   = 9,600,000 B
    const size_t WP_OFF    = 9600000;              // 6912*4  = 27,648 B
    const size_t STATS_OFF = 9627648;              // 64 floats
    unsigned int* xTp   = (unsigned int*)(ws + XT_OFF);
    unsigned int* wp    = (unsigned int*)(ws + WP_OFF);
    float*        stats = (float*)(ws + STATS_OFF);

    const int HBP = (H + 255) / 256;               // 1172 (prep)
    prep<<<HBP, 256, 0, stream>>>(x, w, xTp, wp, stats);

    const int HBC = (H + 127) / 128;               // 2344 (conv: 128 h/block)
    conv<<<HBC, 256, 0, stream>>>(xTp, wp, neigh, out, stats);

    const int NBN = (CO * H / 4 + 255) / 256;      // 9375
    bn_apply<<<NBN, 256, 0, stream>>>(out, stats, gamma, beta);
}